// Round 7
// baseline (4215.440 us; speedup 1.0000x reference)
//
#include <hip/hip_runtime.h>

#define Bn 512
#define Tn 256
#define Fn 128
#define Hn 512
#define KIE 20   // 640/32 k-iters (encoder: [x|h], K=640)
#define KID 16   // 512/32 k-iters (decoder: h only, K=512)
#define NWG 256
#define RS 648   // A_lds row stride in ushorts (16B-aligned)

typedef __attribute__((ext_vector_type(8))) __bf16 bf16x8;
typedef __attribute__((ext_vector_type(4))) float floatx4;

__device__ __forceinline__ unsigned short f2bf_u16(float f) {
  union { float f; unsigned u; } v; v.f = f;
  unsigned r = v.u + 0x7FFFu + ((v.u >> 16) & 1u);   // RNE
  return (unsigned short)(r >> 16);
}

// fast sigmoid/tanh via v_exp_f32 + v_rcp_f32 (error ~1e-6, << bf16 rounding)
__device__ __forceinline__ float sigm(float x) {
  return __builtin_amdgcn_rcpf(1.f + __expf(-x));
}
__device__ __forceinline__ float ftanh(float x) {
  return 1.f - 2.f * __builtin_amdgcn_rcpf(1.f + __expf(2.f * x));
}

// ---- pack encoder weights [x|h] -> B-fragment order [nt][ki][lane][8] ----
__global__ void pack_enc_k(const float* __restrict__ Wih, const float* __restrict__ Whh,
                           unsigned short* __restrict__ Bpe) {
  int id = blockIdx.x;              // nt*KIE + ki
  int nt = id / KIE, ki = id % KIE;
  int l = threadIdx.x;
  int n = nt * 16 + (l & 15);
  int kb = ki * 32 + (l >> 4) * 8;
  __align__(16) unsigned short o[8];
#pragma unroll
  for (int j = 0; j < 8; ++j) {
    int k = kb + j;
    float v = (k < Fn) ? Wih[n * Fn + k] : Whh[n * Hn + (k - Fn)];
    o[j] = f2bf_u16(v);
  }
  *(uint4*)(Bpe + (size_t)(id * 64 + l) * 8) = *(uint4*)o;
}

// ---- pack decoder combined weights (W_hh + W_ih@Wo) -> fragment order ----
__global__ void pack_dec_k(const float* __restrict__ Wih, const float* __restrict__ Whh,
                           const float* __restrict__ Wo, unsigned short* __restrict__ Bpd) {
  int id = blockIdx.x;              // nt*KID + ki
  int nt = id / KID, ki = id % KID;
  int l = threadIdx.x;
  int n = nt * 16 + (l & 15);
  int kb = ki * 32 + (l >> 4) * 8;
  float acc[8];
#pragma unroll
  for (int j = 0; j < 8; ++j) acc[j] = Whh[n * Hn + kb + j];
  for (int f = 0; f < Fn; ++f) {
    float wf = Wih[n * Fn + f];
    const float* wo = Wo + f * Hn + kb;
#pragma unroll
    for (int j = 0; j < 8; ++j) acc[j] += wf * wo[j];
  }
  __align__(16) unsigned short o[8];
#pragma unroll
  for (int j = 0; j < 8; ++j) o[j] = f2bf_u16(acc[j]);
  *(uint4*)(Bpd + (size_t)(id * 64 + l) * 8) = *(uint4*)o;
}

// ---- pack Wo (for y = h@Wo.T) -> fragment order [ft][ki][lane][8] ----
__global__ void pack_wo_k(const float* __restrict__ Wo, unsigned short* __restrict__ Bpw) {
  int id = blockIdx.x;              // ft*KID + ki
  int ft = id / KID, ki = id % KID;
  int l = threadIdx.x;
  int f = ft * 16 + (l & 15);
  int kb = ki * 32 + (l >> 4) * 8;
  __align__(16) unsigned short o[8];
#pragma unroll
  for (int j = 0; j < 8; ++j) o[j] = f2bf_u16(Wo[f * Hn + kb + j]);
  *(uint4*)(Bpw + (size_t)(id * 64 + l) * 8) = *(uint4*)o;
}

// ---- biases: benc = eb_ih+eb_hh ; bdec = db_ih+db_hh + dW_ih@bo ----
__global__ void bias_k(const float* __restrict__ ebih, const float* __restrict__ ebhh,
                       const float* __restrict__ dbih, const float* __restrict__ dbhh,
                       const float* __restrict__ dWih, const float* __restrict__ bo,
                       float* __restrict__ benc, float* __restrict__ bdec) {
  int n = blockIdx.x * blockDim.x + threadIdx.x;  // 2048
  benc[n] = ebih[n] + ebhh[n];
  float a = dbih[n] + dbhh[n];
  for (int f = 0; f < Fn; ++f) a += dWih[n * Fn + f] * bo[f];
  bdec[n] = a;
}

// ---- pack x: ts[b][s][k] fp32 -> xp[s][b][k] bf16 ----
__global__ void pack_x_k(const float* __restrict__ ts, unsigned short* __restrict__ xp) {
  size_t i = (size_t)blockIdx.x * 256 + threadIdx.x;   // quad index
  int k4 = (int)(i & 31);
  size_t bs = i >> 5;
  int s = (int)(bs & 255);
  size_t b = bs >> 8;
  float4 v = *(const float4*)(ts + (i << 2));
  __align__(8) unsigned short o[4];
  o[0] = f2bf_u16(v.x); o[1] = f2bf_u16(v.y); o[2] = f2bf_u16(v.z); o[3] = f2bf_u16(v.w);
  *(unsigned long long*)(xp + ((size_t)s * Bn + b) * Fn + k4 * 4) = *(unsigned long long*)o;
}

// ---- init: zero Hg buffer 0 (512 KB) + flag array (128 KB) ----
__global__ void init_k(unsigned long long* __restrict__ Hg0, unsigned* __restrict__ flg) {
  int i = blockIdx.x * 256 + threadIdx.x;   // 65536
  Hg0[i] = 0ULL;
  if (i < 32768) flg[i] = 0u;
}

// one pipeline slot: stream S of phase p.
// WRITE S -> sync -> EPI (S-1) + publish -> POLL/ISSUE (S+1) -> MFMA S
#define SLOT(S) do { \
  const int Sp = ((S) + 3) & 3, Sn = ((S) + 1) & 3; \
  const int pe = ((S) == 0) ? p - 1 : p; \
  const int pn = ((S) == 3) ? p + 1 : p; \
  /* 1: commit staged regs to LDS */ \
  { uint4 t_; t_.x = (unsigned)hp0; t_.y = (unsigned)(hp0 >> 32); \
    t_.z = (unsigned)hp1; t_.w = (unsigned)(hp1 >> 32); \
    *(uint4*)&A_lds[S][hr * RS + (enc ? Fn : 0) + hc] = t_; \
    if (enc && tid < 256) \
      *(uint2*)&A_lds[S][(tid >> 5) * RS + (tid & 31) * 4] = xpv; } \
  __syncthreads(); \
  /* 2: EPI for (Sp, pe) + immediate per-wave publication */ \
  if (pe >= 0) { \
    const bool ee_ = pe < Tn; \
    if ((w >> 2) == ((Sp) & 1)) { \
      const int idx_ = tid & 255, r_ = idx_ >> 5, j_ = idx_ & 31; \
      float gi_ = gates_lds[Sp][0][r_][j_] + (ee_ ? bie : bid); \
      float gf_ = gates_lds[Sp][1][r_][j_] + (ee_ ? bfe : bfd); \
      float gg_ = gates_lds[Sp][2][r_][j_] + (ee_ ? bge : bgd); \
      float go_ = gates_lds[Sp][3][r_][j_] + (ee_ ? boe : bod); \
      float cin_ = (pe == Tn) ? 0.f : cS[(Sp) >> 1]; \
      float c_ = sigm(gf_) * cin_ + sigm(gi_) * ftanh(gg_); \
      cS[(Sp) >> 1] = c_; \
      float h_ = sigm(go_) * ftanh(c_); \
      __hip_atomic_store(Hg + (size_t)((pe + 1) & 1) * (Bn * Hn) \
          + (size_t)(b0 + (Sp) * 8 + r_) * Hn + j0 + j_, \
          (unsigned short)f2bf_u16(h_), __ATOMIC_RELAXED, __HIP_MEMORY_SCOPE_AGENT); \
      __asm__ __volatile__("s_waitcnt vmcnt(0)" ::: "memory"); \
      if (l == 0) { \
        unsigned o_ = atomicAdd(&cntf[Sp], 1u); \
        if ((o_ & 3u) == 3u) \
          __hip_atomic_store(flg + ((size_t)(Sp) * NWG + wg) * 32, (unsigned)(pe + 1), \
                             __ATOMIC_RELAXED, __HIP_MEMORY_SCOPE_AGENT); \
      } \
    } \
  } \
  /* 3: poll + register-prefetch next slot's stream */ \
  if (pn < 2 * Tn) { \
    if (l < 16) { \
      const unsigned* fp_ = flg + ((size_t)(Sn) * NWG + mg * 16 + l) * 32; \
      while (__hip_atomic_load(fp_, __ATOMIC_RELAXED, __HIP_MEMORY_SCOPE_AGENT) < (unsigned)pn) \
        __builtin_amdgcn_s_sleep(1); \
    } \
    __asm__ __volatile__("" ::: "memory"); \
    const unsigned long long* s_ = (const unsigned long long*) \
        (Hg + (size_t)(pn & 1) * (Bn * Hn) + (size_t)(b0 + (Sn) * 8 + hr) * Hn + hc); \
    hp0 = __hip_atomic_load(s_ + 0, __ATOMIC_RELAXED, __HIP_MEMORY_SCOPE_AGENT); \
    hp1 = __hip_atomic_load(s_ + 1, __ATOMIC_RELAXED, __HIP_MEMORY_SCOPE_AGENT); \
    if (pn < Tn && tid < 256) \
      xpv = *(const uint2*)(xp + ((size_t)pn * Bn + b0 + (Sn) * 8 + (tid >> 5)) * Fn \
                            + (tid & 31) * 4); \
  } \
  /* 4: MFMA (S, p) -> gates (rows 0..7 valid) */ \
  if (enc) { \
    floatx4 acc_ = {0.f, 0.f, 0.f, 0.f}; \
    const unsigned short* Ar_ = &A_lds[S][l15 * RS + q * 8]; \
    _Pragma("unroll") for (int k = 0; k < KIE; ++k) \
      acc_ = __builtin_amdgcn_mfma_f32_16x16x32_bf16(*(const bf16x8*)(Ar_ + k * 32), Bq[k], acc_, 0, 0, 0); \
    if (q < 2) { _Pragma("unroll") for (int r = 0; r < 4; ++r) \
      gates_lds[S][g_][q * 4 + r][nsub * 16 + l15] = acc_[r]; } \
  } else { \
    floatx4 acc_ = {0.f, 0.f, 0.f, 0.f}, accy_ = {0.f, 0.f, 0.f, 0.f}; \
    const bool doY_ = (ns < 8) && (w == (((S) & 1) ? 4 : 0)); \
    const unsigned short* Ar_ = &A_lds[S][l15 * RS + q * 8]; \
    _Pragma("unroll") for (int k = 0; k < KID; ++k) { \
      bf16x8 a_ = *(const bf16x8*)(Ar_ + k * 32); \
      acc_ = __builtin_amdgcn_mfma_f32_16x16x32_bf16(a_, Bd[k], acc_, 0, 0, 0); \
      if (doY_) accy_ = __builtin_amdgcn_mfma_f32_16x16x32_bf16( \
          a_, *(const bf16x8*)&Bw_lds[(k * 64 + l) * 8], accy_, 0, 0, 0); \
    } \
    if (q < 2) { _Pragma("unroll") for (int r = 0; r < 4; ++r) \
      gates_lds[S][g_][q * 4 + r][nsub * 16 + l15] = acc_[r]; } \
    if (doY_ && q < 2) { \
      const int sd_ = p - Tn; \
      _Pragma("unroll") for (int r = 0; r < 4; ++r) \
        __builtin_nontemporal_store(accy_[r] + bof, \
          out + ((size_t)(b0 + (S) * 8 + q * 4 + r) * Tn + (Tn - 1 - sd_)) * Fn + ns * 16 + l15); \
    } \
  } \
} while (0)

// ---- persistent LSTM enc-dec: 256 wgs x 512 thr, 4-stream rotated pipeline ----
__global__ __launch_bounds__(512, 2) void lstm_persist(
    const unsigned short* __restrict__ xp,
    const unsigned short* __restrict__ Bpe,
    const unsigned short* __restrict__ Bpd,
    const unsigned short* __restrict__ Bpw,
    const float* __restrict__ benc,
    const float* __restrict__ bdec,
    const float* __restrict__ bo,
    unsigned short* __restrict__ Hg,   // [2][512][512] bf16 (sc1 access only)
    unsigned* __restrict__ flg,        // [4][256][32] u32 flag lines
    float* __restrict__ out)           // [512][256][128] fp32
{
  const int wg = blockIdx.x;
  const int mg = wg >> 4, ns = wg & 15;
  const int b0 = mg * 32, j0 = ns * 32;
  const int tid = threadIdx.x;
  const int w = tid >> 6, l = tid & 63;
  const int l15 = l & 15, q = l >> 4;
  const int g_ = w >> 1, nsub = w & 1;       // wave = (gate, 16-col subtile)
  const int nt = g_ * 32 + ns * 2 + nsub;
  const int hr = tid >> 6;                   // staging h row 0..7 (= wave)
  const int hc = (tid & 63) * 8;             // staging h col (u16), 16B/thread

  __shared__ __align__(16) unsigned short A_lds[4][16 * RS];     // 82.9 KB (rows 8-15 scratch)
  __shared__ __align__(16) float gates_lds[4][4][8][34];         // 17.4 KB
  __shared__ __align__(16) unsigned short Bw_lds[KID * 64 * 8];  // 16.4 KB
  __shared__ unsigned cntf[4];

  if (tid < 4) cntf[tid] = 0u;

  // ---- preload B tiles (enc + dec) ----
  bf16x8 Bq[KIE], Bd[KID];
  {
    const bf16x8* p_ = (const bf16x8*)Bpe + (size_t)nt * (KIE * 64) + l;
#pragma unroll
    for (int k = 0; k < KIE; ++k) Bq[k] = p_[k * 64];
  }
  {
    const bf16x8* p_ = (const bf16x8*)Bpd + (size_t)nt * (KID * 64) + l;
#pragma unroll
    for (int k = 0; k < KID; ++k) Bd[k] = p_[k * 64];
  }
  // per-thread gate biases (col j = tid&31 of this wg's 32-col slice)
  const int jb = tid & 31;
  const float bie = benc[0 * Hn + j0 + jb], bfe = benc[1 * Hn + j0 + jb];
  const float bge = benc[2 * Hn + j0 + jb], boe = benc[3 * Hn + j0 + jb];
  const float bid = bdec[0 * Hn + j0 + jb], bfd = bdec[1 * Hn + j0 + jb];
  const float bgd = bdec[2 * Hn + j0 + jb], bod = bdec[3 * Hn + j0 + jb];

  if (ns < 8) { // constant Wo slice -> LDS, once
    const uint4* src = (const uint4*)(Bpw + (size_t)ns * (KID * 64 * 8));
    uint4* dst = (uint4*)Bw_lds;
    dst[tid * 2] = src[tid * 2];
    dst[tid * 2 + 1] = src[tid * 2 + 1];
  }
  float bof = 0.f;
  if ((ns < 8) && (w == 0 || w == 4)) bof = bo[ns * 16 + l15];

  float cS[2] = {0.f, 0.f};   // c state: this thread's 2 streams (parity by wave-half)
  unsigned long long hp0, hp1;
  uint2 xpv;

  // prolog: prefetch stream 0, phase 0 (buf 0 zeroed; flags 0 => poll trivially passes)
  {
    const unsigned long long* s_ = (const unsigned long long*)
        (Hg + (size_t)(b0 + hr) * Hn + hc);
    hp0 = __hip_atomic_load(s_ + 0, __ATOMIC_RELAXED, __HIP_MEMORY_SCOPE_AGENT);
    hp1 = __hip_atomic_load(s_ + 1, __ATOMIC_RELAXED, __HIP_MEMORY_SCOPE_AGENT);
    if (tid < 256)
      xpv = *(const uint2*)(xp + ((size_t)(b0 + (tid >> 5))) * Fn + (tid & 31) * 4);
  }

  for (int p = 0; p < 2 * Tn; ++p) {
    const bool enc = p < Tn;
    SLOT(0);
    SLOT(1);
    SLOT(2);
    SLOT(3);
  }
}

extern "C" void kernel_launch(void* const* d_in, const int* in_sizes, int n_in,
                              void* d_out, int out_size, void* d_ws, size_t ws_size,
                              hipStream_t stream) {
  const float* ts   = (const float*)d_in[0];
  const float* eWih = (const float*)d_in[1];
  const float* eWhh = (const float*)d_in[2];
  const float* ebih = (const float*)d_in[3];
  const float* ebhh = (const float*)d_in[4];
  const float* dWih = (const float*)d_in[5];
  const float* dWhh = (const float*)d_in[6];
  const float* dbih = (const float*)d_in[7];
  const float* dbhh = (const float*)d_in[8];
  const float* Wo   = (const float*)d_in[9];
  const float* bo   = (const float*)d_in[10];
  float* outp = (float*)d_out;

  char* ws = (char*)d_ws;
  unsigned short* Bpe  = (unsigned short*)(ws);                 // 2,621,440 B
  unsigned short* Bpd  = (unsigned short*)(ws + 2621440);       // 2,097,152 B
  unsigned short* Bpw  = (unsigned short*)(ws + 4718592);       //   131,072 B
  float*          benc = (float*)(ws + 4849664);                //     8,192 B
  float*          bdec = (float*)(ws + 4857856);                //     8,192 B
  unsigned short* Hg   = (unsigned short*)(ws + 4866048);       // 1,048,576 B
  unsigned*       flg  = (unsigned*)(ws + 5914624);             //   131,072 B
  unsigned short* xp   = (unsigned short*)(ws + 6045696);       // 16,777,216 B

  pack_enc_k<<<128 * KIE, 64, 0, stream>>>(eWih, eWhh, Bpe);
  pack_dec_k<<<128 * KID, 64, 0, stream>>>(dWih, dWhh, Wo, Bpd);
  pack_wo_k<<<8 * KID, 64, 0, stream>>>(Wo, Bpw);
  bias_k<<<8, 256, 0, stream>>>(ebih, ebhh, dbih, dbhh, dWih, bo, benc, bdec);
  pack_x_k<<<16384, 256, 0, stream>>>(ts, xp);
  init_k<<<256, 256, 0, stream>>>((unsigned long long*)Hg, flg);

  lstm_persist<<<NWG, 512, 0, stream>>>(xp, Bpe, Bpd, Bpw, benc, bdec, bo, Hg, flg, outp);
}

// Round 8
// 3724.855 us; speedup vs baseline: 1.1317x; 1.1317x over previous
//
#include <hip/hip_runtime.h>

#define Bn 512
#define Tn 256
#define Fn 128
#define Hn 512
#define KIE 20   // 640/32 k-iters (encoder: [x|h], K=640)
#define KID 16   // 512/32 k-iters (decoder: h only, K=512)
#define NWG 256
#define RS 648   // A_lds row stride in ushorts

typedef __attribute__((ext_vector_type(8))) __bf16 bf16x8;
typedef __attribute__((ext_vector_type(4))) float floatx4;

__device__ __forceinline__ unsigned short f2bf_u16(float f) {
  union { float f; unsigned u; } v; v.f = f;
  unsigned r = v.u + 0x7FFFu + ((v.u >> 16) & 1u);   // RNE
  return (unsigned short)(r >> 16);
}

__device__ __forceinline__ float sigm(float x) {
  return __builtin_amdgcn_rcpf(1.f + __expf(-x));
}
__device__ __forceinline__ float ftanh(float x) {
  return 1.f - 2.f * __builtin_amdgcn_rcpf(1.f + __expf(2.f * x));
}

// intra-stream 4-wave barrier on a monotone LDS counter (no s_barrier!)
__device__ __forceinline__ void wbar(unsigned* c, unsigned tgt, int lane) {
  __asm__ __volatile__("s_waitcnt lgkmcnt(0)" ::: "memory");
  if (lane == 0)
    __hip_atomic_fetch_add(c, 1u, __ATOMIC_RELAXED, __HIP_MEMORY_SCOPE_WORKGROUP);
  while (__hip_atomic_load(c, __ATOMIC_RELAXED, __HIP_MEMORY_SCOPE_WORKGROUP) < tgt) {}
  __asm__ __volatile__("" ::: "memory");
}

// ---- pack encoder weights [x|h] -> B-fragment order [nt][ki][lane][8] ----
__global__ void pack_enc_k(const float* __restrict__ Wih, const float* __restrict__ Whh,
                           unsigned short* __restrict__ Bpe) {
  int id = blockIdx.x;
  int nt = id / KIE, ki = id % KIE;
  int l = threadIdx.x;
  int n = nt * 16 + (l & 15);
  int kb = ki * 32 + (l >> 4) * 8;
  __align__(16) unsigned short o[8];
#pragma unroll
  for (int j = 0; j < 8; ++j) {
    int k = kb + j;
    float v = (k < Fn) ? Wih[n * Fn + k] : Whh[n * Hn + (k - Fn)];
    o[j] = f2bf_u16(v);
  }
  *(uint4*)(Bpe + (size_t)(id * 64 + l) * 8) = *(uint4*)o;
}

// ---- pack decoder combined weights (W_hh + W_ih@Wo) -> fragment order ----
__global__ void pack_dec_k(const float* __restrict__ Wih, const float* __restrict__ Whh,
                           const float* __restrict__ Wo, unsigned short* __restrict__ Bpd) {
  int id = blockIdx.x;
  int nt = id / KID, ki = id % KID;
  int l = threadIdx.x;
  int n = nt * 16 + (l & 15);
  int kb = ki * 32 + (l >> 4) * 8;
  float acc[8];
#pragma unroll
  for (int j = 0; j < 8; ++j) acc[j] = Whh[n * Hn + kb + j];
  for (int f = 0; f < Fn; ++f) {
    float wf = Wih[n * Fn + f];
    const float* wo = Wo + f * Hn + kb;
#pragma unroll
    for (int j = 0; j < 8; ++j) acc[j] += wf * wo[j];
  }
  __align__(16) unsigned short o[8];
#pragma unroll
  for (int j = 0; j < 8; ++j) o[j] = f2bf_u16(acc[j]);
  *(uint4*)(Bpd + (size_t)(id * 64 + l) * 8) = *(uint4*)o;
}

// ---- pack Wo (for y = h@Wo.T) -> fragment order [ft][ki][lane][8] ----
__global__ void pack_wo_k(const float* __restrict__ Wo, unsigned short* __restrict__ Bpw) {
  int id = blockIdx.x;
  int ft = id / KID, ki = id % KID;
  int l = threadIdx.x;
  int f = ft * 16 + (l & 15);
  int kb = ki * 32 + (l >> 4) * 8;
  __align__(16) unsigned short o[8];
#pragma unroll
  for (int j = 0; j < 8; ++j) o[j] = f2bf_u16(Wo[f * Hn + kb + j]);
  *(uint4*)(Bpw + (size_t)(id * 64 + l) * 8) = *(uint4*)o;
}

// ---- biases: benc = eb_ih+eb_hh ; bdec = db_ih+db_hh + dW_ih@bo ----
__global__ void bias_k(const float* __restrict__ ebih, const float* __restrict__ ebhh,
                       const float* __restrict__ dbih, const float* __restrict__ dbhh,
                       const float* __restrict__ dWih, const float* __restrict__ bo,
                       float* __restrict__ benc, float* __restrict__ bdec) {
  int n = blockIdx.x * blockDim.x + threadIdx.x;  // 2048
  benc[n] = ebih[n] + ebhh[n];
  float a = dbih[n] + dbhh[n];
  for (int f = 0; f < Fn; ++f) a += dWih[n * Fn + f] * bo[f];
  bdec[n] = a;
}

// ---- pack x: ts[b][s][k] fp32 -> xp[s][b][k] bf16 ----
__global__ void pack_x_k(const float* __restrict__ ts, unsigned short* __restrict__ xp) {
  size_t i = (size_t)blockIdx.x * 256 + threadIdx.x;
  int k4 = (int)(i & 31);
  size_t bs = i >> 5;
  int s = (int)(bs & 255);
  size_t b = bs >> 8;
  float4 v = *(const float4*)(ts + (i << 2));
  __align__(8) unsigned short o[4];
  o[0] = f2bf_u16(v.x); o[1] = f2bf_u16(v.y); o[2] = f2bf_u16(v.z); o[3] = f2bf_u16(v.w);
  *(unsigned long long*)(xp + ((size_t)s * Bn + b) * Fn + k4 * 4) = *(unsigned long long*)o;
}

// ---- init: zero Hg buffer 0 (512 KB) + flag array ----
__global__ void init_k(unsigned long long* __restrict__ Hg0, unsigned* __restrict__ flg) {
  int i = blockIdx.x * 256 + threadIdx.x;   // 65536
  Hg0[i] = 0ULL;
  if (i < 32768) flg[i] = 0u;
}

// ---- persistent LSTM enc-dec: 256 wgs x 512 thr, 2 decoupled wave-streams ----
__global__ __launch_bounds__(512, 2) void lstm_persist(
    const unsigned short* __restrict__ xp,
    const unsigned short* __restrict__ Bpe,
    const unsigned short* __restrict__ Bpd,
    const unsigned short* __restrict__ Bpw,
    const float* __restrict__ benc,
    const float* __restrict__ bdec,
    const float* __restrict__ bo,
    unsigned short* __restrict__ Hg,   // [2][512][512] bf16 (sc1 access only)
    unsigned* __restrict__ flg,        // [2][256][32] u32 flag lines
    float* __restrict__ out)           // [512][256][128] fp32
{
  const int wg = blockIdx.x;
  const int mg = wg >> 4, ns = wg & 15;
  const int b0 = mg * 32, j0 = ns * 32;
  const int tid = threadIdx.x;
  const int w = tid >> 6, l = tid & 63;
  const int l15 = l & 15, q = l >> 4;
  const int S = w >> 2;                  // stream 0/1 (waves 0-3 / 4-7)
  const int w2 = w & 3;                  // wave-in-stream = gate index
  const int t = (w2 << 6) | l;           // thread id within stream 0..255
  const int r16 = t & 15;                // staging/EPI row (swizzled: 2-way LDS banks)
  const int c16 = t >> 4;                // staging/EPI col group 0..15
  const int bb = b0 + S * 16;            // this stream's first batch row

  __shared__ __align__(16) unsigned short A_lds[2][16 * RS];     // 41.5 KB
  __shared__ __align__(16) float gates_lds[2][4][16][34];        // 17.4 KB
  __shared__ __align__(16) unsigned short Bw_lds[KID * 64 * 8];  // 16.4 KB
  __shared__ unsigned barc[2], pubc[2];

  if (tid < 2) { barc[tid] = 0u; pubc[tid] = 0u; }

  // ---- preload encoder B tiles: gate w2, 2 n-tiles ----
  const int nt0 = w2 * 32 + ns * 2;
  bf16x8 BR0[KIE], BR1[KIE];
  {
    const bf16x8* p_ = (const bf16x8*)Bpe + (size_t)nt0 * (KIE * 64) + l;
#pragma unroll
    for (int k = 0; k < KIE; ++k) { BR0[k] = p_[k * 64]; BR1[k] = p_[(KIE + k) * 64]; }
  }
  // per-thread encoder biases (cols j0 + c16*2, +1)
  float2 fbi = *(const float2*)(benc + 0 * Hn + j0 + c16 * 2);
  float2 fbf = *(const float2*)(benc + 1 * Hn + j0 + c16 * 2);
  float2 fbg = *(const float2*)(benc + 2 * Hn + j0 + c16 * 2);
  float2 fbo = *(const float2*)(benc + 3 * Hn + j0 + c16 * 2);

  if (ns < 8) { // constant Wo slice -> LDS, once
    const uint4* src = (const uint4*)(Bpw + (size_t)ns * (KID * 64 * 8));
    uint4* dst = (uint4*)Bw_lds;
    dst[tid * 2] = src[tid * 2];
    dst[tid * 2 + 1] = src[tid * 2 + 1];
  }
  const bool yw = (ns < 8) && (w2 == 0);
  float bof = 0.f;
  if (yw) bof = bo[ns * 16 + l15];

  float cE = 0.f, cO = 0.f;
  // prefetch x(0) for this stream
  uint4 xv = *(const uint4*)(xp + ((size_t)(bb + r16)) * Fn + c16 * 8);

  __syncthreads();   // ONE wg-wide barrier: Bw_lds + counters visible. None in loop.

  unsigned bt = 0;
  for (int p = 0; p < 2 * Tn; ++p) {
    const bool enc = p < Tn;
    if (p == Tn) {   // reload decoder weights + biases (private regs; stream-local timing)
      const bf16x8* p_ = (const bf16x8*)Bpd + (size_t)nt0 * (KID * 64) + l;
#pragma unroll
      for (int k = 0; k < KID; ++k) { BR0[k] = p_[k * 64]; BR1[k] = p_[(KID + k) * 64]; }
      fbi = *(const float2*)(bdec + 0 * Hn + j0 + c16 * 2);
      fbf = *(const float2*)(bdec + 1 * Hn + j0 + c16 * 2);
      fbg = *(const float2*)(bdec + 2 * Hn + j0 + c16 * 2);
      fbo = *(const float2*)(bdec + 3 * Hn + j0 + c16 * 2);
    }

    // ---- poll own stream's 16 producer flags for phase p (per-wave, independent) ----
    if (l < 16) {
      const unsigned* fp_ = flg + ((size_t)S * NWG + mg * 16 + l) * 32;
      while (__hip_atomic_load(fp_, __ATOMIC_RELAXED, __HIP_MEMORY_SCOPE_AGENT) < (unsigned)p)
        __builtin_amdgcn_s_sleep(1);
    }
    __asm__ __volatile__("" ::: "memory");

    // ---- load h(p): 64 B/thread (32 cols), stage into LDS ----
    {
      const unsigned long long* hs = (const unsigned long long*)
          (Hg + (size_t)(p & 1) * (Bn * Hn) + (size_t)(bb + r16) * Hn + c16 * 32);
      unsigned long long hv[8];
#pragma unroll
      for (int i = 0; i < 8; ++i)
        hv[i] = __hip_atomic_load(hs + i, __ATOMIC_RELAXED, __HIP_MEMORY_SCOPE_AGENT);
      const int off = enc ? Fn : 0;
      unsigned short* dst = &A_lds[S][r16 * RS + off + c16 * 32];
#pragma unroll
      for (int i = 0; i < 4; ++i) {
        uint4 t_;
        t_.x = (unsigned)hv[2 * i];     t_.y = (unsigned)(hv[2 * i] >> 32);
        t_.z = (unsigned)hv[2 * i + 1]; t_.w = (unsigned)(hv[2 * i + 1] >> 32);
        *(uint4*)(dst + i * 8) = t_;
      }
      if (enc) *(uint4*)&A_lds[S][r16 * RS + c16 * 8] = xv;
    }
    bt += 4; wbar(&barc[S], bt, l);      // bar1: stream's A-tile staged

    // prefetch next x (flies under MFMA+EPI)
    if (enc) {
      int sn = (p + 1 < Tn) ? p + 1 : Tn - 1;
      xv = *(const uint4*)(xp + ((size_t)sn * Bn + bb + r16) * Fn + c16 * 8);
    }

    // ---- MFMA: gate w2, 2 n-tiles, M=16 ----
    floatx4 a0 = {0.f, 0.f, 0.f, 0.f}, a1 = {0.f, 0.f, 0.f, 0.f};
    floatx4 ay = {0.f, 0.f, 0.f, 0.f};
    const unsigned short* Ar = &A_lds[S][l15 * RS + q * 8];
    if (enc) {
#pragma unroll
      for (int k = 0; k < KIE; ++k) {
        bf16x8 af = *(const bf16x8*)(Ar + k * 32);
        a0 = __builtin_amdgcn_mfma_f32_16x16x32_bf16(af, BR0[k], a0, 0, 0, 0);
        a1 = __builtin_amdgcn_mfma_f32_16x16x32_bf16(af, BR1[k], a1, 0, 0, 0);
      }
    } else {
#pragma unroll
      for (int k = 0; k < KID; ++k) {
        bf16x8 af = *(const bf16x8*)(Ar + k * 32);
        a0 = __builtin_amdgcn_mfma_f32_16x16x32_bf16(af, BR0[k], a0, 0, 0, 0);
        a1 = __builtin_amdgcn_mfma_f32_16x16x32_bf16(af, BR1[k], a1, 0, 0, 0);
        if (yw)
          ay = __builtin_amdgcn_mfma_f32_16x16x32_bf16(
              af, *(const bf16x8*)&Bw_lds[(k * 64 + l) * 8], ay, 0, 0, 0);
      }
    }
#pragma unroll
    for (int r = 0; r < 4; ++r) {
      gates_lds[S][w2][q * 4 + r][l15] = a0[r];
      gates_lds[S][w2][q * 4 + r][16 + l15] = a1[r];
    }
    bt += 4; wbar(&barc[S], bt, l);      // bar2: gates ready (also fences A_lds reads)

    // ---- EPI: 2 h-cols/thread; tagged-free h store; publish via LDS fan-in ----
    {
      float2 g0 = *(const float2*)&gates_lds[S][0][r16][c16 * 2];
      float2 g1 = *(const float2*)&gates_lds[S][1][r16][c16 * 2];
      float2 g2 = *(const float2*)&gates_lds[S][2][r16][c16 * 2];
      float2 g3 = *(const float2*)&gates_lds[S][3][r16][c16 * 2];
      float ciE = (p == Tn) ? 0.f : cE;
      float ciO = (p == Tn) ? 0.f : cO;
      cE = sigm(g1.x + fbf.x) * ciE + sigm(g0.x + fbi.x) * ftanh(g2.x + fbg.x);
      cO = sigm(g1.y + fbf.y) * ciO + sigm(g0.y + fbi.y) * ftanh(g2.y + fbg.y);
      float hE = sigm(g3.x + fbo.x) * ftanh(cE);
      float hO = sigm(g3.y + fbo.y) * ftanh(cO);
      unsigned hv_ = (unsigned)f2bf_u16(hE) | ((unsigned)f2bf_u16(hO) << 16);
      __hip_atomic_store((unsigned*)(Hg + (size_t)((p + 1) & 1) * (Bn * Hn)
                         + (size_t)(bb + r16) * Hn + j0 + c16 * 2),
                         hv_, __ATOMIC_RELAXED, __HIP_MEMORY_SCOPE_AGENT);
    }
    __asm__ __volatile__("s_waitcnt vmcnt(0)" ::: "memory");
    if (l == 0) {
      unsigned o_ = __hip_atomic_fetch_add(&pubc[S], 1u,
                      __ATOMIC_RELAXED, __HIP_MEMORY_SCOPE_WORKGROUP);
      if (o_ == (unsigned)(p * 4 + 3))
        __hip_atomic_store(flg + ((size_t)S * NWG + wg) * 32, (unsigned)(p + 1),
                           __ATOMIC_RELAXED, __HIP_MEMORY_SCOPE_AGENT);
    }

    // ---- y output (decoder, off critical path) ----
    if (yw && !enc) {
      int sd = p - Tn;
#pragma unroll
      for (int r = 0; r < 4; ++r)
        __builtin_nontemporal_store(ay[r] + bof,
          out + ((size_t)(bb + q * 4 + r) * Tn + (Tn - 1 - sd)) * Fn + ns * 16 + l15);
    }
  }
}

extern "C" void kernel_launch(void* const* d_in, const int* in_sizes, int n_in,
                              void* d_out, int out_size, void* d_ws, size_t ws_size,
                              hipStream_t stream) {
  const float* ts   = (const float*)d_in[0];
  const float* eWih = (const float*)d_in[1];
  const float* eWhh = (const float*)d_in[2];
  const float* ebih = (const float*)d_in[3];
  const float* ebhh = (const float*)d_in[4];
  const float* dWih = (const float*)d_in[5];
  const float* dWhh = (const float*)d_in[6];
  const float* dbih = (const float*)d_in[7];
  const float* dbhh = (const float*)d_in[8];
  const float* Wo   = (const float*)d_in[9];
  const float* bo   = (const float*)d_in[10];
  float* outp = (float*)d_out;

  char* ws = (char*)d_ws;
  unsigned short* Bpe  = (unsigned short*)(ws);                 // 2,621,440 B
  unsigned short* Bpd  = (unsigned short*)(ws + 2621440);       // 2,097,152 B
  unsigned short* Bpw  = (unsigned short*)(ws + 4718592);       //   131,072 B
  float*          benc = (float*)(ws + 4849664);                //     8,192 B
  float*          bdec = (float*)(ws + 4857856);                //     8,192 B
  unsigned short* Hg   = (unsigned short*)(ws + 4866048);       // 1,048,576 B
  unsigned*       flg  = (unsigned*)(ws + 5914624);             //   131,072 B
  unsigned short* xp   = (unsigned short*)(ws + 6045696);       // 16,777,216 B

  pack_enc_k<<<128 * KIE, 64, 0, stream>>>(eWih, eWhh, Bpe);
  pack_dec_k<<<128 * KID, 64, 0, stream>>>(dWih, dWhh, Wo, Bpd);
  pack_wo_k<<<8 * KID, 64, 0, stream>>>(Wo, Bpw);
  bias_k<<<8, 256, 0, stream>>>(ebih, ebhh, dbih, dbhh, dWih, bo, benc, bdec);
  pack_x_k<<<16384, 256, 0, stream>>>(ts, xp);
  init_k<<<256, 256, 0, stream>>>((unsigned long long*)Hg, flg);

  lstm_persist<<<NWG, 512, 0, stream>>>(xp, Bpe, Bpd, Bpw, benc, bdec, bo, Hg, flg, outp);
}

// Round 9
// 3154.238 us; speedup vs baseline: 1.3364x; 1.1809x over previous
//
#include <hip/hip_runtime.h>

#define Bn 512
#define Tn 256
#define Fn 128
#define Hn 512
#define KIE 20   // 640/32 k-iters (encoder: [x|h], K=640)
#define KID 16   // 512/32 k-iters (decoder: h only, K=512)
#define NWG 512  // 32 groups x 16 wgs; 2 wgs/CU
#define RS 648   // A_lds row stride in ushorts

typedef __attribute__((ext_vector_type(8))) __bf16 bf16x8;
typedef __attribute__((ext_vector_type(4))) float floatx4;

__device__ __forceinline__ unsigned short f2bf_u16(float f) {
  union { float f; unsigned u; } v; v.f = f;
  unsigned r = v.u + 0x7FFFu + ((v.u >> 16) & 1u);   // RNE
  return (unsigned short)(r >> 16);
}

__device__ __forceinline__ float sigm(float x) {
  return __builtin_amdgcn_rcpf(1.f + __expf(-x));
}
__device__ __forceinline__ float ftanh(float x) {
  return 1.f - 2.f * __builtin_amdgcn_rcpf(1.f + __expf(2.f * x));
}

// ---- pack encoder weights [x|h] -> B-fragment order [nt][ki][lane][8] ----
__global__ void pack_enc_k(const float* __restrict__ Wih, const float* __restrict__ Whh,
                           unsigned short* __restrict__ Bpe) {
  int id = blockIdx.x;
  int nt = id / KIE, ki = id % KIE;
  int l = threadIdx.x;
  int n = nt * 16 + (l & 15);
  int kb = ki * 32 + (l >> 4) * 8;
  __align__(16) unsigned short o[8];
#pragma unroll
  for (int j = 0; j < 8; ++j) {
    int k = kb + j;
    float v = (k < Fn) ? Wih[n * Fn + k] : Whh[n * Hn + (k - Fn)];
    o[j] = f2bf_u16(v);
  }
  *(uint4*)(Bpe + (size_t)(id * 64 + l) * 8) = *(uint4*)o;
}

// ---- pack decoder combined weights (W_hh + W_ih@Wo) -> fragment order ----
__global__ void pack_dec_k(const float* __restrict__ Wih, const float* __restrict__ Whh,
                           const float* __restrict__ Wo, unsigned short* __restrict__ Bpd) {
  int id = blockIdx.x;
  int nt = id / KID, ki = id % KID;
  int l = threadIdx.x;
  int n = nt * 16 + (l & 15);
  int kb = ki * 32 + (l >> 4) * 8;
  float acc[8];
#pragma unroll
  for (int j = 0; j < 8; ++j) acc[j] = Whh[n * Hn + kb + j];
  for (int f = 0; f < Fn; ++f) {
    float wf = Wih[n * Fn + f];
    const float* wo = Wo + f * Hn + kb;
#pragma unroll
    for (int j = 0; j < 8; ++j) acc[j] += wf * wo[j];
  }
  __align__(16) unsigned short o[8];
#pragma unroll
  for (int j = 0; j < 8; ++j) o[j] = f2bf_u16(acc[j]);
  *(uint4*)(Bpd + (size_t)(id * 64 + l) * 8) = *(uint4*)o;
}

// ---- pack Wo (for y = h@Wo.T) -> fragment order [ft][ki][lane][8] ----
__global__ void pack_wo_k(const float* __restrict__ Wo, unsigned short* __restrict__ Bpw) {
  int id = blockIdx.x;
  int ft = id / KID, ki = id % KID;
  int l = threadIdx.x;
  int f = ft * 16 + (l & 15);
  int kb = ki * 32 + (l >> 4) * 8;
  __align__(16) unsigned short o[8];
#pragma unroll
  for (int j = 0; j < 8; ++j) o[j] = f2bf_u16(Wo[f * Hn + kb + j]);
  *(uint4*)(Bpw + (size_t)(id * 64 + l) * 8) = *(uint4*)o;
}

// ---- biases: benc = eb_ih+eb_hh ; bdec = db_ih+db_hh + dW_ih@bo ----
__global__ void bias_k(const float* __restrict__ ebih, const float* __restrict__ ebhh,
                       const float* __restrict__ dbih, const float* __restrict__ dbhh,
                       const float* __restrict__ dWih, const float* __restrict__ bo,
                       float* __restrict__ benc, float* __restrict__ bdec) {
  int n = blockIdx.x * blockDim.x + threadIdx.x;  // 2048
  benc[n] = ebih[n] + ebhh[n];
  float a = dbih[n] + dbhh[n];
  for (int f = 0; f < Fn; ++f) a += dWih[n * Fn + f] * bo[f];
  bdec[n] = a;
}

// ---- pack x: ts[b][s][k] fp32 -> xp[s][b][k] bf16 ----
__global__ void pack_x_k(const float* __restrict__ ts, unsigned short* __restrict__ xp) {
  size_t i = (size_t)blockIdx.x * 256 + threadIdx.x;
  int k4 = (int)(i & 31);
  size_t bs = i >> 5;
  int s = (int)(bs & 255);
  size_t b = bs >> 8;
  float4 v = *(const float4*)(ts + (i << 2));
  __align__(8) unsigned short o[4];
  o[0] = f2bf_u16(v.x); o[1] = f2bf_u16(v.y); o[2] = f2bf_u16(v.z); o[3] = f2bf_u16(v.w);
  *(unsigned long long*)(xp + ((size_t)s * Bn + b) * Fn + k4 * 4) = *(unsigned long long*)o;
}

// ---- init: zero Hg buffer 0 (512 KB) + flag array (64 KB) ----
__global__ void init_k(unsigned long long* __restrict__ Hg0, unsigned* __restrict__ flg) {
  int i = blockIdx.x * 256 + threadIdx.x;   // 65536
  Hg0[i] = 0ULL;
  if (i < 16384) flg[i] = 0u;
}

// ---- persistent LSTM enc-dec: 512 wgs x 256 thr (2 wgs/CU), simple skeleton ----
__global__ __launch_bounds__(256, 2) void lstm_persist(
    const unsigned short* __restrict__ xp,
    const unsigned short* __restrict__ Bpe,
    const unsigned short* __restrict__ Bpd,
    const unsigned short* __restrict__ Bpw,
    const float* __restrict__ benc,
    const float* __restrict__ bdec,
    const float* __restrict__ bo,
    unsigned short* __restrict__ Hg,   // [2][512][512] bf16 (sc1 access only)
    unsigned* __restrict__ flg,        // [512][32] u32 flag lines, monotone phase
    float* __restrict__ out)           // [512][256][128] fp32
{
  const int wg = blockIdx.x;             // 0..511
  const int g = wg >> 4, ns = wg & 15;   // group (16 batch rows), N-slice
  const int b0 = g * 16, j0 = ns * 32;
  const int tid = threadIdx.x;           // 0..255
  const int w = tid >> 6, l = tid & 63;  // wave = gate
  const int l15 = l & 15, q = l >> 4;
  const int nt0 = w * 32 + ns * 2;       // this wave's two 16-col gate tiles
  const int r16 = tid >> 4;              // staging/EPI row 0..15
  const int c16 = tid & 15;              // staging/EPI col group

  __shared__ __align__(16) unsigned short A_lds[16 * RS];        // 20.7 KB
  __shared__ __align__(16) float gates_lds[4][16][34];           //  8.7 KB
  __shared__ __align__(16) unsigned short Bw_lds[KID * 64 * 8];  // 16.4 KB

  // ---- preload encoder B tiles: wave = gate w, 2 n-tiles ----
  bf16x8 BR0[KIE], BR1[KIE];
  {
    const bf16x8* p_ = (const bf16x8*)Bpe + (size_t)nt0 * (KIE * 64) + l;
#pragma unroll
    for (int k = 0; k < KIE; ++k) { BR0[k] = p_[k * 64]; BR1[k] = p_[(KIE + k) * 64]; }
  }
  // per-thread gate biases (cols j0 + c16*2, +1)
  float2 fbi = *(const float2*)(benc + 0 * Hn + j0 + c16 * 2);
  float2 fbf = *(const float2*)(benc + 1 * Hn + j0 + c16 * 2);
  float2 fbg = *(const float2*)(benc + 2 * Hn + j0 + c16 * 2);
  float2 fbo = *(const float2*)(benc + 3 * Hn + j0 + c16 * 2);

  if (ns < 8) { // constant Wo slice -> LDS, once (1024 uint4 / 256 thr = 4 each)
    const uint4* src = (const uint4*)(Bpw + (size_t)ns * (KID * 64 * 8));
    uint4* dst = (uint4*)Bw_lds;
#pragma unroll
    for (int i = 0; i < 4; ++i) dst[tid * 4 + i] = src[tid * 4 + i];
  }
  const bool yw = (ns < 8) && (w == 0);
  float bof = 0.f;
  if (yw) bof = bo[ns * 16 + l15];

  float cE = 0.f, cO = 0.f;
  // prefetch x(0)
  uint4 xv = *(const uint4*)(xp + ((size_t)(b0 + r16)) * Fn + c16 * 8);

  __syncthreads();   // Bw_lds visible

  for (int p = 0; p < 2 * Tn; ++p) {
    const bool enc = p < Tn;
    if (p == Tn) {   // switch to decoder weights/biases; c restarts at zero
      const bf16x8* p_ = (const bf16x8*)Bpd + (size_t)nt0 * (KID * 64) + l;
#pragma unroll
      for (int k = 0; k < KID; ++k) { BR0[k] = p_[k * 64]; BR1[k] = p_[(KID + k) * 64]; }
      fbi = *(const float2*)(bdec + 0 * Hn + j0 + c16 * 2);
      fbf = *(const float2*)(bdec + 1 * Hn + j0 + c16 * 2);
      fbg = *(const float2*)(bdec + 2 * Hn + j0 + c16 * 2);
      fbo = *(const float2*)(bdec + 3 * Hn + j0 + c16 * 2);
      cE = 0.f; cO = 0.f;
    }

    // ---- poll own group's 16 producer flags for phase p ----
    if (l < 16) {
      const unsigned* fp_ = flg + (size_t)(g * 16 + l) * 32;
      while (__hip_atomic_load(fp_, __ATOMIC_RELAXED, __HIP_MEMORY_SCOPE_AGENT) < (unsigned)p)
        __builtin_amdgcn_s_sleep(1);
    }
    __asm__ __volatile__("" ::: "memory");

    // ---- stage h(p) (+x for encoder) into A_lds ----
    {
      const unsigned long long* hs = (const unsigned long long*)
          (Hg + (size_t)(p & 1) * (Bn * Hn) + (size_t)(b0 + r16) * Hn + c16 * 32);
      unsigned long long hv[8];
#pragma unroll
      for (int i = 0; i < 8; ++i)
        hv[i] = __hip_atomic_load(hs + i, __ATOMIC_RELAXED, __HIP_MEMORY_SCOPE_AGENT);
      const int off = enc ? Fn : 0;
      unsigned short* dst = &A_lds[r16 * RS + off + c16 * 32];
#pragma unroll
      for (int i = 0; i < 4; ++i) {
        uint4 t_;
        t_.x = (unsigned)hv[2 * i];     t_.y = (unsigned)(hv[2 * i] >> 32);
        t_.z = (unsigned)hv[2 * i + 1]; t_.w = (unsigned)(hv[2 * i + 1] >> 32);
        *(uint4*)(dst + i * 8) = t_;
      }
      if (enc) *(uint4*)&A_lds[r16 * RS + c16 * 8] = xv;
    }
    __syncthreads();   // sync1: A ready

    // prefetch next x (flies under MFMA)
    if (enc) {
      int sn = (p + 1 < Tn) ? p + 1 : Tn - 1;
      xv = *(const uint4*)(xp + ((size_t)sn * Bn + b0 + r16) * Fn + c16 * 8);
    }

    // ---- MFMA: gate w, 2 n-tiles, M=16 ----
    floatx4 a0 = {0.f, 0.f, 0.f, 0.f}, a1 = {0.f, 0.f, 0.f, 0.f};
    floatx4 ay = {0.f, 0.f, 0.f, 0.f};
    const unsigned short* Ar = &A_lds[l15 * RS + q * 8];
    if (enc) {
#pragma unroll
      for (int k = 0; k < KIE; ++k) {
        bf16x8 af = *(const bf16x8*)(Ar + k * 32);
        a0 = __builtin_amdgcn_mfma_f32_16x16x32_bf16(af, BR0[k], a0, 0, 0, 0);
        a1 = __builtin_amdgcn_mfma_f32_16x16x32_bf16(af, BR1[k], a1, 0, 0, 0);
      }
    } else {
#pragma unroll
      for (int k = 0; k < KID; ++k) {
        bf16x8 af = *(const bf16x8*)(Ar + k * 32);
        a0 = __builtin_amdgcn_mfma_f32_16x16x32_bf16(af, BR0[k], a0, 0, 0, 0);
        a1 = __builtin_amdgcn_mfma_f32_16x16x32_bf16(af, BR1[k], a1, 0, 0, 0);
        if (yw)
          ay = __builtin_amdgcn_mfma_f32_16x16x32_bf16(
              af, *(const bf16x8*)&Bw_lds[(k * 64 + l) * 8], ay, 0, 0, 0);
      }
    }
#pragma unroll
    for (int r = 0; r < 4; ++r) {
      gates_lds[w][q * 4 + r][l15] = a0[r];
      gates_lds[w][q * 4 + r][16 + l15] = a1[r];
    }
    __syncthreads();   // sync2: gates ready

    // ---- EPI: 2 h-cols/thread ----
    {
      float2 g0 = *(const float2*)&gates_lds[0][r16][c16 * 2];
      float2 g1 = *(const float2*)&gates_lds[1][r16][c16 * 2];
      float2 g2 = *(const float2*)&gates_lds[2][r16][c16 * 2];
      float2 g3 = *(const float2*)&gates_lds[3][r16][c16 * 2];
      cE = sigm(g1.x + fbf.x) * cE + sigm(g0.x + fbi.x) * ftanh(g2.x + fbg.x);
      cO = sigm(g1.y + fbf.y) * cO + sigm(g0.y + fbi.y) * ftanh(g2.y + fbg.y);
      float hE = sigm(g3.x + fbo.x) * ftanh(cE);
      float hO = sigm(g3.y + fbo.y) * ftanh(cO);
      unsigned hv_ = (unsigned)f2bf_u16(hE) | ((unsigned)f2bf_u16(hO) << 16);
      __hip_atomic_store((unsigned*)(Hg + (size_t)((p + 1) & 1) * (Bn * Hn)
                         + (size_t)(b0 + r16) * Hn + j0 + c16 * 2),
                         hv_, __ATOMIC_RELAXED, __HIP_MEMORY_SCOPE_AGENT);
    }
    // ---- y output (decoder; off critical path) ----
    if (yw && !enc) {
      int sd = p - Tn;
#pragma unroll
      for (int r = 0; r < 4; ++r)
        __builtin_nontemporal_store(ay[r] + bof,
          out + ((size_t)(b0 + q * 4 + r) * Tn + (Tn - 1 - sd)) * Fn + ns * 16 + l15);
    }
    __syncthreads();   // sync3: vmcnt drained by all waves (compiler-inserted wait)
    if (tid == 0)
      __hip_atomic_store(flg + (size_t)wg * 32, (unsigned)(p + 1),
                         __ATOMIC_RELAXED, __HIP_MEMORY_SCOPE_AGENT);
  }
}

extern "C" void kernel_launch(void* const* d_in, const int* in_sizes, int n_in,
                              void* d_out, int out_size, void* d_ws, size_t ws_size,
                              hipStream_t stream) {
  const float* ts   = (const float*)d_in[0];
  const float* eWih = (const float*)d_in[1];
  const float* eWhh = (const float*)d_in[2];
  const float* ebih = (const float*)d_in[3];
  const float* ebhh = (const float*)d_in[4];
  const float* dWih = (const float*)d_in[5];
  const float* dWhh = (const float*)d_in[6];
  const float* dbih = (const float*)d_in[7];
  const float* dbhh = (const float*)d_in[8];
  const float* Wo   = (const float*)d_in[9];
  const float* bo   = (const float*)d_in[10];
  float* outp = (float*)d_out;

  char* ws = (char*)d_ws;
  unsigned short* Bpe  = (unsigned short*)(ws);                 // 2,621,440 B
  unsigned short* Bpd  = (unsigned short*)(ws + 2621440);       // 2,097,152 B
  unsigned short* Bpw  = (unsigned short*)(ws + 4718592);       //   131,072 B
  float*          benc = (float*)(ws + 4849664);                //     8,192 B
  float*          bdec = (float*)(ws + 4857856);                //     8,192 B
  unsigned short* Hg   = (unsigned short*)(ws + 4866048);       // 1,048,576 B
  unsigned*       flg  = (unsigned*)(ws + 5914624);             //    65,536 B
  unsigned short* xp   = (unsigned short*)(ws + 5980160);       // 16,777,216 B

  pack_enc_k<<<128 * KIE, 64, 0, stream>>>(eWih, eWhh, Bpe);
  pack_dec_k<<<128 * KID, 64, 0, stream>>>(dWih, dWhh, Wo, Bpd);
  pack_wo_k<<<8 * KID, 64, 0, stream>>>(Wo, Bpw);
  bias_k<<<8, 256, 0, stream>>>(ebih, ebhh, dbih, dbhh, dWih, bo, benc, bdec);
  pack_x_k<<<16384, 256, 0, stream>>>(ts, xp);
  init_k<<<256, 256, 0, stream>>>((unsigned long long*)Hg, flg);

  lstm_persist<<<NWG, 256, 0, stream>>>(xp, Bpe, Bpd, Bpw, benc, bdec, bo, Hg, flg, outp);
}